// Round 1
// baseline (217.923 us; speedup 1.0000x reference)
//
#include <hip/hip_runtime.h>

#define B_ 8
#define C_ 512
#define T_ 2048
#define N_TOK 16384
#define K_CB 4096

typedef __attribute__((ext_vector_type(4))) float f32x4;
typedef __attribute__((ext_vector_type(8))) short short8;

static __device__ __forceinline__ unsigned short f2bf(float f) {
    unsigned u = __float_as_uint(f);
    unsigned r = (u + 0x7FFFu + ((u >> 16) & 1u)) >> 16;  // RNE
    return (unsigned short)r;
}

// ---------------- Kernel 1: transpose student (B,C,T)->(N,C) bf16 + per-token stats ----------------
__global__ __launch_bounds__(256) void k1_prep(
    const float* __restrict__ student,   // (B,C,T) fp32
    const int* __restrict__ codes,       // (B,T) int32
    const float* __restrict__ codebook,  // (K,C) fp32
    unsigned short* __restrict__ Abf,    // (N,C) bf16 out
    float* __restrict__ xnorm, float* __restrict__ dtarg,
    float* __restrict__ accum)
{
    __shared__ float tile[64][65];
    __shared__ int lcodes[64];
    __shared__ float wsum[8];
    int tid = threadIdx.x;
    int b = blockIdx.x >> 5;            // 32 t-tiles per batch
    int t0 = (blockIdx.x & 31) << 6;
    int cx = tid & 63;                  // lane
    int q  = tid >> 6;                  // wave
    if (tid < 64) lcodes[tid] = codes[b * T_ + t0 + tid];
    __syncthreads();
    float ax2[16], ad2[16];
#pragma unroll
    for (int p = 0; p < 16; ++p) { ax2[p] = 0.f; ad2[p] = 0.f; }
    for (int c0 = 0; c0 < C_; c0 += 64) {
#pragma unroll
        for (int p = 0; p < 16; ++p) {
            int ch = p * 4 + q;
            tile[ch][cx] = student[(size_t)b * (C_ * T_) + (size_t)(c0 + ch) * T_ + t0 + cx];
        }
        __syncthreads();
#pragma unroll
        for (int p = 0; p < 16; ++p) {
            int ty = p * 4 + q;
            float x = tile[cx][ty];
            int n = b * T_ + t0 + ty;
            Abf[(size_t)n * C_ + c0 + cx] = f2bf(x);
            ax2[p] += x * x;
            float cb = codebook[(size_t)lcodes[ty] * C_ + c0 + cx];
            float d = x - cb;
            ad2[p] += d * d;
        }
        __syncthreads();
    }
    float sq_local = 0.f, td_local = 0.f;
#pragma unroll
    for (int p = 0; p < 16; ++p) {
        float sx = ax2[p], sd = ad2[p];
#pragma unroll
        for (int m = 1; m < 64; m <<= 1) {
            sx += __shfl_xor(sx, m);
            sd += __shfl_xor(sd, m);
        }
        if (cx == 0) {
            int n = b * T_ + t0 + p * 4 + q;
            xnorm[n] = sx;
            float dt = sqrtf(sd);
            dtarg[n] = dt;
            sq_local += sd;
            td_local += dt;
        }
    }
    if (cx == 0) { wsum[q] = sq_local; wsum[4 + q] = td_local; }
    __syncthreads();
    if (tid == 0) {
        atomicAdd(&accum[2], wsum[0] + wsum[1] + wsum[2] + wsum[3]);
        atomicAdd(&accum[3], wsum[4] + wsum[5] + wsum[6] + wsum[7]);
    }
}

// ---------------- Kernel 1b: codebook -> bf16 + row norms ----------------
__global__ __launch_bounds__(256) void k1_cb(
    const float* __restrict__ codebook,
    unsigned short* __restrict__ CBbf,
    float* __restrict__ cbnorm)
{
    int tid = threadIdx.x;
    int lane = tid & 63;
    int w = tid >> 6;
    int row = blockIdx.x * 4 + w;
    const float* src = codebook + (size_t)row * C_ + lane * 8;
    float4 v0 = *(const float4*)(src);
    float4 v1 = *(const float4*)(src + 4);
    float s = v0.x*v0.x + v0.y*v0.y + v0.z*v0.z + v0.w*v0.w
            + v1.x*v1.x + v1.y*v1.y + v1.z*v1.z + v1.w*v1.w;
    uint4 pk;
    pk.x = (unsigned)f2bf(v0.x) | ((unsigned)f2bf(v0.y) << 16);
    pk.y = (unsigned)f2bf(v0.z) | ((unsigned)f2bf(v0.w) << 16);
    pk.z = (unsigned)f2bf(v1.x) | ((unsigned)f2bf(v1.y) << 16);
    pk.w = (unsigned)f2bf(v1.z) | ((unsigned)f2bf(v1.w) << 16);
    *(uint4*)(CBbf + (size_t)row * C_ + lane * 8) = pk;
#pragma unroll
    for (int m = 1; m < 64; m <<= 1) s += __shfl_xor(s, m);
    if (lane == 0) cbnorm[row] = s;
}

// ---------------- Kernel 2: fused bf16 MFMA GEMM + distance/softmax/argmin epilogue ----------------
// grid = (N/128 row-blocks) x (4 col-splits); block = 256 (4 waves, 2x2 of 64x64 each)
__global__ __launch_bounds__(256, 2) void k2_main(
    const unsigned short* __restrict__ Abf,
    const unsigned short* __restrict__ CBbf,
    const float* __restrict__ xnorm,
    const float* __restrict__ dtarg,
    const float* __restrict__ cbnorm,
    float* __restrict__ s_sum,
    unsigned long long* __restrict__ minpack)
{
    __shared__ __align__(16) unsigned short a_lds[128 * 32];
    __shared__ __align__(16) unsigned short b_lds[128 * 32];
    int tid = threadIdx.x;
    int lane = tid & 63;
    int wave = tid >> 6;
    int wr = wave >> 1, wc = wave & 1;
    int l15 = lane & 15, hi = lane >> 4;
    int rb = blockIdx.x >> 2;
    int cs = blockIdx.x & 3;
    int row0 = rb * 128;
    int colbase = cs * 1024;

    int sr = tid >> 2;                 // staging row 0..63
    int sk = (tid & 3) * 8;            // bf16 k-offset
    const unsigned short* pA1 = Abf + (size_t)(row0 + sr) * C_ + sk;
    const unsigned short* pA2 = Abf + (size_t)(row0 + 64 + sr) * C_ + sk;
    unsigned short* dA1 = a_lds + tid * 8;
    unsigned short* dA2 = a_lds + (tid + 256) * 8;
    unsigned short* dB1 = b_lds + tid * 8;
    unsigned short* dB2 = b_lds + (tid + 256) * 8;

    float sacc[4][4], mind[4][4];
    unsigned midx[4][4];
#pragma unroll
    for (int rt = 0; rt < 4; ++rt)
#pragma unroll
        for (int r = 0; r < 4; ++r) {
            sacc[rt][r] = 0.f; mind[rt][r] = 3.4e38f; midx[rt][r] = 0u;
        }

    for (int cc = 0; cc < 8; ++cc) {
        int col0 = colbase + cc * 128;
        const unsigned short* pB1 = CBbf + (size_t)(col0 + sr) * C_ + sk;
        const unsigned short* pB2 = CBbf + (size_t)(col0 + 64 + sr) * C_ + sk;
        f32x4 acc[4][4];
#pragma unroll
        for (int rt = 0; rt < 4; ++rt)
#pragma unroll
            for (int ct = 0; ct < 4; ++ct)
                acc[rt][ct] = (f32x4){0.f, 0.f, 0.f, 0.f};

        uint4 ra1 = *(const uint4*)(pA1);
        uint4 ra2 = *(const uint4*)(pA2);
        uint4 rb1 = *(const uint4*)(pB1);
        uint4 rb2 = *(const uint4*)(pB2);
        for (int ks = 0; ks < 16; ++ks) {
            *(uint4*)dA1 = ra1;
            *(uint4*)dA2 = ra2;
            *(uint4*)dB1 = rb1;
            *(uint4*)dB2 = rb2;
            __syncthreads();
            if (ks < 15) {               // prefetch next k-step under the MFMAs
                int ko = (ks + 1) * 32;
                ra1 = *(const uint4*)(pA1 + ko);
                ra2 = *(const uint4*)(pA2 + ko);
                rb1 = *(const uint4*)(pB1 + ko);
                rb2 = *(const uint4*)(pB2 + ko);
            }
            short8 af[4], bfr[4];
#pragma unroll
            for (int rt = 0; rt < 4; ++rt)
                af[rt] = *(const short8*)(a_lds + ((wr * 64 + rt * 16 + l15) * 32 + hi * 8));
#pragma unroll
            for (int ct = 0; ct < 4; ++ct)
                bfr[ct] = *(const short8*)(b_lds + ((wc * 64 + ct * 16 + l15) * 32 + hi * 8));
#pragma unroll
            for (int rt = 0; rt < 4; ++rt)
#pragma unroll
                for (int ct = 0; ct < 4; ++ct)
                    acc[rt][ct] = __builtin_amdgcn_mfma_f32_16x16x32_bf16(af[rt], bfr[ct], acc[rt][ct], 0, 0, 0);
            __syncthreads();
        }
        // epilogue: dot -> distance -> exp-sum + argmin
        float cbn[4];
#pragma unroll
        for (int ct = 0; ct < 4; ++ct)
            cbn[ct] = cbnorm[col0 + wc * 64 + ct * 16 + l15];
#pragma unroll
        for (int rt = 0; rt < 4; ++rt) {
#pragma unroll
            for (int r = 0; r < 4; ++r) {
                int row = row0 + wr * 64 + rt * 16 + hi * 4 + r;
                float xn = xnorm[row];
                float dt = dtarg[row];
#pragma unroll
                for (int ct = 0; ct < 4; ++ct) {
                    float dot = acc[rt][ct][r];
                    float d2 = fmaxf(xn + cbn[ct] - 2.f * dot, 0.f);
                    float d = sqrtf(d2);
                    sacc[rt][r] += __expf(fminf(dt - d, 80.f));
                    int col = col0 + wc * 64 + ct * 16 + l15;
                    if (d < mind[rt][r]) { mind[rt][r] = d; midx[rt][r] = (unsigned)col; }
                }
            }
        }
    }
    // reduce across the 16 lanes (l15) sharing each row, then merge atomically
#pragma unroll
    for (int rt = 0; rt < 4; ++rt)
#pragma unroll
        for (int r = 0; r < 4; ++r) {
            float sv = sacc[rt][r];
            float dm = mind[rt][r];
            unsigned ix = midx[rt][r];
#pragma unroll
            for (int m = 1; m < 16; m <<= 1) {
                sv += __shfl_xor(sv, m);
                float od = __shfl_xor(dm, m);
                unsigned oi = __shfl_xor(ix, m);
                if (od < dm || (od == dm && oi < ix)) { dm = od; ix = oi; }
            }
            if (l15 == 0) {
                int row = row0 + wr * 64 + rt * 16 + hi * 4 + r;
                atomicAdd(&s_sum[row], sv);
                unsigned long long pk = ((unsigned long long)__float_as_uint(dm) << 32) | (unsigned long long)ix;
                atomicMin(&minpack[row], pk);
            }
        }
}

// ---------------- Kernel 3a: per-token CE/accuracy reduce ----------------
__global__ __launch_bounds__(256) void k3a(
    const float* __restrict__ s_sum,
    const unsigned long long* __restrict__ minpack,
    const int* __restrict__ codes,
    float* __restrict__ accum)
{
    __shared__ float wce[4], wac[4];
    int tid = threadIdx.x;
    int n = blockIdx.x * 256 + tid;
    float ce = logf(s_sum[n]);
    unsigned pred = (unsigned)(minpack[n] & 0xFFFFFFFFull);
    float ok = (pred == (unsigned)codes[n]) ? 1.f : 0.f;
#pragma unroll
    for (int m = 1; m < 64; m <<= 1) {
        ce += __shfl_xor(ce, m);
        ok += __shfl_xor(ok, m);
    }
    int lane = tid & 63, w = tid >> 6;
    if (lane == 0) { wce[w] = ce; wac[w] = ok; }
    __syncthreads();
    if (tid == 0) {
        atomicAdd(&accum[0], wce[0] + wce[1] + wce[2] + wce[3]);
        atomicAdd(&accum[1], wac[0] + wac[1] + wac[2] + wac[3]);
    }
}

// ---------------- Kernel 3b: finalize 5 outputs ----------------
__global__ void k3b(const float* __restrict__ accum, float* __restrict__ out)
{
    if (threadIdx.x == 0 && blockIdx.x == 0) {
        float ce   = accum[0] / (float)N_TOK;
        float accy = accum[1] / (float)N_TOK;
        float emb  = accum[2] / ((float)N_TOK * (float)C_);
        float td   = accum[3] / (float)N_TOK;
        out[0] = emb + ce;   // total_loss (EMB_W=CE_W=1)
        out[1] = emb;        // emb_to_codebook_loss
        out[2] = ce;         // ce_loss
        out[3] = accy;       // token_accuracy
        out[4] = td;         // emb_to_target_dist
    }
}

extern "C" void kernel_launch(void* const* d_in, const int* in_sizes, int n_in,
                              void* d_out, int out_size, void* d_ws, size_t ws_size,
                              hipStream_t stream)
{
    const float* student  = (const float*)d_in[0];
    const int*   codes    = (const int*)d_in[1];
    const float* codebook = (const float*)d_in[2];
    // d_in[3] distance_matrix is unused by the reference.
    float* out = (float*)d_out;

    char* ws = (char*)d_ws;
    unsigned short* Abf   = (unsigned short*)(ws);                 // 16 MiB
    unsigned short* CBbf  = (unsigned short*)(ws + 16777216);      // 4 MiB
    float* xnorm          = (float*)(ws + 20971520);               // 64 KiB
    float* dtarg          = (float*)(ws + 21037056);               // 64 KiB
    float* cbnorm         = (float*)(ws + 21102592);               // 16 KiB
    float* s_sum          = (float*)(ws + 21118976);               // 64 KiB
    unsigned long long* minpack = (unsigned long long*)(ws + 21184512); // 128 KiB
    float* accum          = (float*)(ws + 21315584);               // 64 B

    hipMemsetAsync(s_sum, 0, 65536, stream);
    hipMemsetAsync(minpack, 0xFF, 131072, stream);
    hipMemsetAsync(accum, 0, 64, stream);

    hipLaunchKernelGGL(k1_prep, dim3(256), dim3(256), 0, stream,
                       student, codes, codebook, Abf, xnorm, dtarg, accum);
    hipLaunchKernelGGL(k1_cb, dim3(1024), dim3(256), 0, stream,
                       codebook, CBbf, cbnorm);
    hipLaunchKernelGGL(k2_main, dim3(512), dim3(256), 0, stream,
                       Abf, CBbf, xnorm, dtarg, cbnorm, s_sum, minpack);
    hipLaunchKernelGGL(k3a, dim3(64), dim3(256), 0, stream,
                       s_sum, minpack, codes, accum);
    hipLaunchKernelGGL(k3b, dim3(1), dim3(64), 0, stream, accum, out);
}